// Round 1
// baseline (5478.901 us; speedup 1.0000x reference)
//
#include <hip/hip_runtime.h>

constexpr int NN  = 100000;
constexpr int NE  = 3200000;
constexpr int CIN = 128;
constexpr int CH  = 16;   // hidden
constexpr int CO  = 64;   // out

__global__ void k_init_deg(float* __restrict__ deg) {
    int i = blockIdx.x * 256 + threadIdx.x;
    if (i < NN) deg[i] = 1.0f;   // self-loop contributes 1
}

__global__ void k_deg_count(const int* __restrict__ cols, float* __restrict__ deg) {
    int e = blockIdx.x * 256 + threadIdx.x;
    if (e >= NE) return;
    int c = cols[e];
    if ((unsigned)c < (unsigned)NN) atomicAdd(&deg[c], 1.0f);
}

__global__ void k_dis(float* __restrict__ deg) {
    int i = blockIdx.x * 256 + threadIdx.x;
    if (i < NN) deg[i] = rsqrtf(deg[i]);   // deg >= 1 always
}

// h1 = x @ W1   (NN x 128) @ (128 x 16)
__global__ void __launch_bounds__(256) k_gemm1(const float* __restrict__ x,
                                               const float* __restrict__ W1,
                                               float* __restrict__ h1) {
    __shared__ float xs[32][CIN + 1];      // +1 pad: kill 8-way bank conflict
    __shared__ float ws[CIN][CH];
    int t = threadIdx.x;
    int base = blockIdx.x * 32;            // 100000 = 32*3125 exactly
    for (int i = t; i < CIN * CH; i += 256) ws[i >> 4][i & 15] = W1[i];
    const float4* xv = (const float4*)(x + (size_t)base * CIN);
    for (int i = t; i < 32 * CIN / 4; i += 256) {
        float4 v = xv[i];
        int r = i >> 5, cq = i & 31;
        xs[r][cq * 4 + 0] = v.x; xs[r][cq * 4 + 1] = v.y;
        xs[r][cq * 4 + 2] = v.z; xs[r][cq * 4 + 3] = v.w;
    }
    __syncthreads();
    int node = t >> 3;            // 0..31
    int c0 = (t & 7) * 2;         // 0,2,..,14
    float a0 = 0.f, a1 = 0.f;
#pragma unroll 8
    for (int k = 0; k < CIN; ++k) {
        float xk = xs[node][k];
        a0 += xk * ws[k][c0];
        a1 += xk * ws[k][c0 + 1];
    }
    float2* o = (float2*)(h1 + (size_t)(base + node) * CH + c0);
    *o = make_float2(a0, a1);
}

// agg[col] += dis[row]*dis[col] * h[row]   over all edges (16 channels)
__global__ void k_scatter(const int* __restrict__ rows, const int* __restrict__ cols,
                          const float* __restrict__ dis, const float* __restrict__ h,
                          float* __restrict__ agg) {
    int e = blockIdx.x * 256 + threadIdx.x;
    if (e >= NE) return;
    int r = rows[e], c = cols[e];
    if ((unsigned)r >= (unsigned)NN || (unsigned)c >= (unsigned)NN) return;
    float nrm = dis[r] * dis[c];
    const float4* hv = (const float4*)(h + (size_t)r * CH);
    float4 v0 = hv[0], v1 = hv[1], v2 = hv[2], v3 = hv[3];
    float* o = agg + (size_t)c * CH;
    atomicAdd(o + 0,  v0.x * nrm); atomicAdd(o + 1,  v0.y * nrm);
    atomicAdd(o + 2,  v0.z * nrm); atomicAdd(o + 3,  v0.w * nrm);
    atomicAdd(o + 4,  v1.x * nrm); atomicAdd(o + 5,  v1.y * nrm);
    atomicAdd(o + 6,  v1.z * nrm); atomicAdd(o + 7,  v1.w * nrm);
    atomicAdd(o + 8,  v2.x * nrm); atomicAdd(o + 9,  v2.y * nrm);
    atomicAdd(o + 10, v2.z * nrm); atomicAdd(o + 11, v2.w * nrm);
    atomicAdd(o + 12, v3.x * nrm); atomicAdd(o + 13, v3.y * nrm);
    atomicAdd(o + 14, v3.z * nrm); atomicAdd(o + 15, v3.w * nrm);
}

// h1 <- relu(agg1 + dis^2 * h1 + b1)   (adds the self-loop message, in place)
__global__ void k_relu_self(const float* __restrict__ agg1, const float* __restrict__ dis,
                            const float* __restrict__ b1, float* __restrict__ h1) {
    int i = blockIdx.x * 256 + threadIdx.x;     // quad index over NN*16/4
    if (i >= NN * CH / 4) return;
    int node = i >> 2, q = i & 3;
    float d = dis[node], d2 = d * d;
    float4 a = ((const float4*)agg1)[i];
    float4 h = ((const float4*)h1)[i];
    float4 b = ((const float4*)b1)[q];
    float4 r;
    r.x = fmaxf(a.x + d2 * h.x + b.x, 0.f);
    r.y = fmaxf(a.y + d2 * h.y + b.y, 0.f);
    r.z = fmaxf(a.z + d2 * h.z + b.z, 0.f);
    r.w = fmaxf(a.w + d2 * h.w + b.w, 0.f);
    ((float4*)h1)[i] = r;
}

// out = sigmoid((agg2 + dis^2*hr) @ W2 + b2)
__global__ void __launch_bounds__(256) k_final(const float* __restrict__ agg2,
                                               const float* __restrict__ hr,
                                               const float* __restrict__ dis,
                                               const float* __restrict__ W2,
                                               const float* __restrict__ b2,
                                               float* __restrict__ out) {
    __shared__ float w2s[CH][CO];   // 4 KB
    __shared__ float vs[4][CH];
    int t = threadIdx.x;            // 256 = 4 nodes x 64 outs
    for (int i = t; i < CH * CO; i += 256) w2s[i >> 6][i & 63] = W2[i];
    int nl = t >> 6;
    int o  = t & 63;
    int node = blockIdx.x * 4 + nl;     // 100000 = 4*25000 exactly
    if (o < CH) {
        float d = dis[node];
        size_t idx = (size_t)node * CH + o;
        vs[nl][o] = agg2[idx] + d * d * hr[idx];
    }
    __syncthreads();
    float acc = b2[o];
#pragma unroll
    for (int c = 0; c < CH; ++c) acc += vs[nl][c] * w2s[c][o];
    out[(size_t)node * CO + o] = 1.0f / (1.0f + __expf(-acc));
}

extern "C" void kernel_launch(void* const* d_in, const int* in_sizes, int n_in,
                              void* d_out, int out_size, void* d_ws, size_t ws_size,
                              hipStream_t stream) {
    const float* x  = (const float*)d_in[0];
    const int*   ei = (const int*)d_in[1];
    const float* W1 = (const float*)d_in[2];
    const float* b1 = (const float*)d_in[3];
    const float* W2 = (const float*)d_in[4];
    const float* b2 = (const float*)d_in[5];
    float* out = (float*)d_out;

    float* ws   = (float*)d_ws;
    float* deg  = ws;                        // NN (also holds dis after k_dis)
    float* h1   = ws + 100096;               // NN*CH  (later hr, in place)
    float* agg1 = h1 + (size_t)NN * CH;      // NN*CH
    float* agg2 = agg1 + (size_t)NN * CH;    // NN*CH

    const int* rows = ei;
    const int* cols = ei + NE;

    // zero both aggregation buffers (contiguous)
    hipMemsetAsync(agg1, 0, (size_t)NN * CH * 2 * sizeof(float), stream);

    k_init_deg <<<(NN + 255) / 256, 256, 0, stream>>>(deg);
    k_deg_count<<<NE / 256,        256, 0, stream>>>(cols, deg);
    k_dis      <<<(NN + 255) / 256, 256, 0, stream>>>(deg);
    k_gemm1    <<<NN / 32,          256, 0, stream>>>(x, W1, h1);
    k_scatter  <<<NE / 256,        256, 0, stream>>>(rows, cols, deg, h1, agg1);
    k_relu_self<<<(NN * CH / 4 + 255) / 256, 256, 0, stream>>>(agg1, deg, b1, h1);
    k_scatter  <<<NE / 256,        256, 0, stream>>>(rows, cols, deg, h1, agg2);
    k_final    <<<NN / 4,          256, 0, stream>>>(agg2, h1, deg, W2, b2, out);
}

// Round 2
// 741.244 us; speedup vs baseline: 7.3915x; 7.3915x over previous
//
#include <hip/hip_runtime.h>

constexpr int NN  = 100000;
constexpr int NE  = 3200000;
constexpr int CIN = 128;
constexpr int CH  = 16;   // hidden
constexpr int CO  = 64;   // out

// ---- CSR build ----------------------------------------------------------

__global__ void k_count(const int* __restrict__ cols, int* __restrict__ cnt) {
    int e = blockIdx.x * 256 + threadIdx.x;
    if (e >= NE) return;
    int c = cols[e];
    if ((unsigned)c < (unsigned)NN) atomicAdd(&cnt[c], 1);
}

__global__ void k_dis(const int* __restrict__ cnt, float* __restrict__ dis) {
    int i = blockIdx.x * 256 + threadIdx.x;
    if (i < NN) dis[i] = rsqrtf((float)(cnt[i] + 1));   // +1 self-loop
}

// single-block exclusive scan of cnt -> cursor (1024 threads, 98 items each)
__global__ void __launch_bounds__(1024) k_scan(const int* __restrict__ cnt,
                                               int* __restrict__ cursor) {
    __shared__ int sh[1024];
    const int CHUNK = 98;           // 98*1024 >= 100000
    int t = threadIdx.x;
    int lo = t * CHUNK, hi = min(lo + CHUNK, NN);
    int s = 0;
    for (int i = lo; i < hi; ++i) s += cnt[i];
    sh[t] = s;
    __syncthreads();
    for (int off = 1; off < 1024; off <<= 1) {
        int add = (t >= off) ? sh[t - off] : 0;
        __syncthreads();
        sh[t] += add;
        __syncthreads();
    }
    int run = sh[t] - s;            // exclusive prefix of this chunk
    for (int i = lo; i < hi; ++i) { cursor[i] = run; run += cnt[i]; }
}

__global__ void k_fill(const int* __restrict__ rows, const int* __restrict__ cols,
                       int* __restrict__ cursor, int* __restrict__ csr_rid) {
    int e = blockIdx.x * 256 + threadIdx.x;
    if (e >= NE) return;
    int r = rows[e], c = cols[e];
    if ((unsigned)r >= (unsigned)NN || (unsigned)c >= (unsigned)NN) return;
    int pos = atomicAdd(&cursor[c], 1);
    csr_rid[pos] = r;
}
// after k_fill, cursor[i] == end of node i's segment; start = end - cnt[i]

// ---- layer math ---------------------------------------------------------

// g = dis[node] * (x @ W1)   (NN x 128) @ (128 x 16), scaled
__global__ void __launch_bounds__(256) k_gemm1s(const float* __restrict__ x,
                                                const float* __restrict__ W1,
                                                const float* __restrict__ dis,
                                                float* __restrict__ g) {
    __shared__ float xs[32][CIN + 1];
    __shared__ float ws[CIN][CH];
    int t = threadIdx.x;
    int base = blockIdx.x * 32;            // 100000 = 32*3125
    for (int i = t; i < CIN * CH; i += 256) ws[i >> 4][i & 15] = W1[i];
    const float4* xv = (const float4*)(x + (size_t)base * CIN);
    for (int i = t; i < 32 * CIN / 4; i += 256) {
        float4 v = xv[i];
        int r = i >> 5, cq = i & 31;
        xs[r][cq * 4 + 0] = v.x; xs[r][cq * 4 + 1] = v.y;
        xs[r][cq * 4 + 2] = v.z; xs[r][cq * 4 + 3] = v.w;
    }
    __syncthreads();
    int node = t >> 3;            // 0..31
    int c0 = (t & 7) * 2;
    float a0 = 0.f, a1 = 0.f;
#pragma unroll 8
    for (int k = 0; k < CIN; ++k) {
        float xk = xs[node][k];
        a0 += xk * ws[k][c0];
        a1 += xk * ws[k][c0 + 1];
    }
    float d = dis[base + node];
    float2* o = (float2*)(g + (size_t)(base + node) * CH + c0);
    *o = make_float2(a0 * d, a1 * d);
}

// A[c] = dis[c] * ( sum_{edges into c} g[row] + g[c] )   (16 ch, 16 lanes/node)
__global__ void __launch_bounds__(256) k_gather(const int* __restrict__ csr_rid,
                                                const int* __restrict__ cursor,
                                                const int* __restrict__ cnt,
                                                const float* __restrict__ dis,
                                                const float* __restrict__ g,
                                                float* __restrict__ A) {
    int t = threadIdx.x;
    int node = blockIdx.x * 16 + (t >> 4);   // 100000 = 16*6250
    int ch = t & 15;
    int end = cursor[node];
    int n   = cnt[node];
    float acc = g[(size_t)node * CH + ch];   // self-loop term
    int e = end - n;
    for (; e + 1 < end; e += 2) {            // 2-way ILP on the dependent loads
        int r0 = csr_rid[e], r1 = csr_rid[e + 1];
        float v0 = g[(size_t)r0 * CH + ch];
        float v1 = g[(size_t)r1 * CH + ch];
        acc += v0; acc += v1;
    }
    if (e < end) acc += g[(size_t)csr_rid[e] * CH + ch];
    A[(size_t)node * CH + ch] = dis[node] * acc;
}

// g <- dis * relu(A + b1)    (prepares scaled layer-2 input, overwrites g)
__global__ void k_mid(const float* __restrict__ A, const float* __restrict__ dis,
                      const float* __restrict__ b1, float* __restrict__ g) {
    int i = blockIdx.x * 256 + threadIdx.x;   // quad index over NN*16/4
    if (i >= NN * CH / 4) return;
    int node = i >> 2, q = i & 3;
    float d = dis[node];
    float4 a = ((const float4*)A)[i];
    float4 b = ((const float4*)b1)[q];
    float4 r;
    r.x = d * fmaxf(a.x + b.x, 0.f);
    r.y = d * fmaxf(a.y + b.y, 0.f);
    r.z = d * fmaxf(a.z + b.z, 0.f);
    r.w = d * fmaxf(a.w + b.w, 0.f);
    ((float4*)g)[i] = r;
}

// out = sigmoid(A2 @ W2 + b2)
__global__ void __launch_bounds__(256) k_final(const float* __restrict__ A2,
                                               const float* __restrict__ W2,
                                               const float* __restrict__ b2,
                                               float* __restrict__ out) {
    __shared__ float w2s[CH][CO];   // 4 KB
    __shared__ float vs[4][CH];
    int t = threadIdx.x;            // 256 = 4 nodes x 64 outs
    for (int i = t; i < CH * CO; i += 256) w2s[i >> 6][i & 63] = W2[i];
    int nl = t >> 6;
    int o  = t & 63;
    int node = blockIdx.x * 4 + nl;     // 100000 = 4*25000
    if (o < CH) vs[nl][o] = A2[(size_t)node * CH + o];
    __syncthreads();
    float acc = b2[o];
#pragma unroll
    for (int c = 0; c < CH; ++c) acc += vs[nl][c] * w2s[c][o];
    out[(size_t)node * CO + o] = 1.0f / (1.0f + __expf(-acc));
}

extern "C" void kernel_launch(void* const* d_in, const int* in_sizes, int n_in,
                              void* d_out, int out_size, void* d_ws, size_t ws_size,
                              hipStream_t stream) {
    const float* x  = (const float*)d_in[0];
    const int*   ei = (const int*)d_in[1];
    const float* W1 = (const float*)d_in[2];
    const float* b1 = (const float*)d_in[3];
    const float* W2 = (const float*)d_in[4];
    const float* b2 = (const float*)d_in[5];
    float* out = (float*)d_out;

    const int* rows = ei;
    const int* cols = ei + NE;

    char* w = (char*)d_ws;
    int*   cnt     = (int*)w;                 w += 100096 * 4;
    int*   cursor  = (int*)w;                 w += 100096 * 4;
    float* dis     = (float*)w;               w += 100096 * 4;
    int*   csr_rid = (int*)w;                 w += (size_t)NE * 4;
    float* g       = (float*)w;               w += (size_t)NN * CH * 4;
    float* A       = (float*)w;               // NN*CH floats

    hipMemsetAsync(cnt, 0, NN * sizeof(int), stream);

    k_count <<<NE / 256,        256, 0, stream>>>(cols, cnt);
    k_dis   <<<(NN + 255) / 256, 256, 0, stream>>>(cnt, dis);
    k_scan  <<<1,              1024, 0, stream>>>(cnt, cursor);
    k_fill  <<<NE / 256,        256, 0, stream>>>(rows, cols, cursor, csr_rid);
    k_gemm1s<<<NN / 32,         256, 0, stream>>>(x, W1, dis, g);
    k_gather<<<NN / 16,         256, 0, stream>>>(csr_rid, cursor, cnt, dis, g, A);
    k_mid   <<<(NN * CH / 4 + 255) / 256, 256, 0, stream>>>(A, dis, b1, g);
    k_gather<<<NN / 16,         256, 0, stream>>>(csr_rid, cursor, cnt, dis, g, A);
    k_final <<<NN / 4,          256, 0, stream>>>(A, W2, b2, out);
}

// Round 3
// 326.404 us; speedup vs baseline: 16.7856x; 2.2709x over previous
//
#include <hip/hip_runtime.h>

constexpr int NN  = 100000;
constexpr int NE  = 3200000;
constexpr int CIN = 128;
constexpr int CH  = 16;   // hidden
constexpr int CO  = 64;   // out

// ---- CSR build: single atomic pass --------------------------------------

// rank[e] = position of edge e within its destination's segment; cnt accumulates degree
__global__ void k_rank(const int* __restrict__ cols, int* __restrict__ cnt,
                       int* __restrict__ rank) {
    int i = blockIdx.x * 256 + threadIdx.x;      // over NE/4
    if (i >= NE / 4) return;
    int4 c = ((const int4*)cols)[i];
    int4 r;
    r.x = atomicAdd(&cnt[c.x], 1);
    r.y = atomicAdd(&cnt[c.y], 1);
    r.z = atomicAdd(&cnt[c.z], 1);
    r.w = atomicAdd(&cnt[c.w], 1);
    ((int4*)rank)[i] = r;
}

// block-level exclusive scan (1024/block) + block sums; fold in dis = rsqrt(deg+1)
__global__ void __launch_bounds__(1024) k_scan1(const int* __restrict__ cnt,
                                                int* __restrict__ cursor,
                                                int* __restrict__ bsum,
                                                float* __restrict__ dis) {
    __shared__ int sh[1024];
    int t = threadIdx.x;
    int i = blockIdx.x * 1024 + t;
    int v = (i < NN) ? cnt[i] : 0;
    if (i < NN) dis[i] = rsqrtf((float)(v + 1));
    sh[t] = v;
    __syncthreads();
    for (int off = 1; off < 1024; off <<= 1) {
        int a = (t >= off) ? sh[t - off] : 0;
        __syncthreads();
        sh[t] += a;
        __syncthreads();
    }
    if (i < NN) cursor[i] = sh[t] - v;            // exclusive within block
    if (t == 1023) bsum[blockIdx.x] = sh[1023];
}

__global__ void k_scan2(int* __restrict__ bsum) { // exclusive scan of 98 block sums
    __shared__ int sh[128];
    int t = threadIdx.x;
    int v = (t < 98) ? bsum[t] : 0;
    sh[t] = v;
    __syncthreads();
    for (int off = 1; off < 128; off <<= 1) {
        int a = (t >= off) ? sh[t - off] : 0;
        __syncthreads();
        sh[t] += a;
        __syncthreads();
    }
    if (t < 98) bsum[t] = sh[t] - v;
}

__global__ void k_scan3(int* __restrict__ cursor, const int* __restrict__ bsum) {
    int i = blockIdx.x * 256 + threadIdx.x;
    if (i < NN) cursor[i] += bsum[i >> 10];
}

// csr_rid[cursor[c] + rank[e]] = row[e]   -- no atomics, only the scattered store
__global__ void k_place(const int* __restrict__ rows, const int* __restrict__ cols,
                        const int* __restrict__ rank, const int* __restrict__ cursor,
                        int* __restrict__ csr_rid) {
    int i = blockIdx.x * 256 + threadIdx.x;      // over NE/4
    if (i >= NE / 4) return;
    int4 r = ((const int4*)rows)[i];
    int4 c = ((const int4*)cols)[i];
    int4 k = ((const int4*)rank)[i];
    csr_rid[cursor[c.x] + k.x] = r.x;
    csr_rid[cursor[c.y] + k.y] = r.y;
    csr_rid[cursor[c.z] + k.z] = r.z;
    csr_rid[cursor[c.w] + k.w] = r.w;
}

// ---- layer math ---------------------------------------------------------

// g = dis[node] * (x @ W1)
__global__ void __launch_bounds__(256) k_gemm1s(const float* __restrict__ x,
                                                const float* __restrict__ W1,
                                                const float* __restrict__ dis,
                                                float* __restrict__ g) {
    __shared__ float xs[32][CIN + 1];
    __shared__ float ws[CIN][CH];
    int t = threadIdx.x;
    int base = blockIdx.x * 32;                  // 100000 = 32*3125
    for (int i = t; i < CIN * CH; i += 256) ws[i >> 4][i & 15] = W1[i];
    const float4* xv = (const float4*)(x + (size_t)base * CIN);
    for (int i = t; i < 32 * CIN / 4; i += 256) {
        float4 v = xv[i];
        int r = i >> 5, cq = i & 31;
        xs[r][cq * 4 + 0] = v.x; xs[r][cq * 4 + 1] = v.y;
        xs[r][cq * 4 + 2] = v.z; xs[r][cq * 4 + 3] = v.w;
    }
    __syncthreads();
    int node = t >> 3;
    int c0 = (t & 7) * 2;
    float a0 = 0.f, a1 = 0.f;
#pragma unroll 8
    for (int k = 0; k < CIN; ++k) {
        float xk = xs[node][k];
        a0 += xk * ws[k][c0];
        a1 += xk * ws[k][c0 + 1];
    }
    float d = dis[base + node];
    float2* o = (float2*)(g + (size_t)(base + node) * CH + c0);
    *o = make_float2(a0 * d, a1 * d);
}

// layer-1 gather fused with mid: g2 = dis * relu(dis*(sum + self) + b1)
// 4 lanes per node, float4 per lane, 4-way unrolled chains
__global__ void __launch_bounds__(256) k_gather1(const int* __restrict__ csr_rid,
                                                 const int* __restrict__ cursor,
                                                 const int* __restrict__ cnt,
                                                 const float* __restrict__ dis,
                                                 const float* __restrict__ g,
                                                 const float* __restrict__ b1,
                                                 float* __restrict__ g2) {
    int t = threadIdx.x;
    int node = blockIdx.x * 64 + (t >> 2);
    if (node >= NN) return;
    int q = t & 3;
    const float4* g4 = (const float4*)g;
    int start = cursor[node], n = cnt[node];
    float4 acc = g4[node * 4 + q];               // self-loop term
    int e = start, end = start + n;
    for (; e + 3 < end; e += 4) {
        int r0 = csr_rid[e], r1 = csr_rid[e + 1], r2 = csr_rid[e + 2], r3 = csr_rid[e + 3];
        float4 v0 = g4[r0 * 4 + q], v1 = g4[r1 * 4 + q];
        float4 v2 = g4[r2 * 4 + q], v3 = g4[r3 * 4 + q];
        acc.x += (v0.x + v1.x) + (v2.x + v3.x);
        acc.y += (v0.y + v1.y) + (v2.y + v3.y);
        acc.z += (v0.z + v1.z) + (v2.z + v3.z);
        acc.w += (v0.w + v1.w) + (v2.w + v3.w);
    }
    for (; e < end; ++e) {
        float4 v = g4[csr_rid[e] * 4 + q];
        acc.x += v.x; acc.y += v.y; acc.z += v.z; acc.w += v.w;
    }
    float d = dis[node];
    float4 b = ((const float4*)b1)[q];
    float4 r;
    r.x = d * fmaxf(d * acc.x + b.x, 0.f);
    r.y = d * fmaxf(d * acc.y + b.y, 0.f);
    r.z = d * fmaxf(d * acc.z + b.z, 0.f);
    r.w = d * fmaxf(d * acc.w + b.w, 0.f);
    ((float4*)g2)[node * 4 + q] = r;
}

// layer-2 gather fused with final GEMM + sigmoid
__global__ void __launch_bounds__(256) k_gather2(const int* __restrict__ csr_rid,
                                                 const int* __restrict__ cursor,
                                                 const int* __restrict__ cnt,
                                                 const float* __restrict__ dis,
                                                 const float* __restrict__ g2,
                                                 const float* __restrict__ W2,
                                                 const float* __restrict__ b2,
                                                 float* __restrict__ out) {
    __shared__ float vs[64][CH + 1];
    __shared__ float w2s[CH][CO];
    int t = threadIdx.x;
    for (int i = t; i < CH * CO; i += 256) w2s[i >> 6][i & 63] = W2[i];
    int nl = t >> 2, q = t & 3;
    int node = blockIdx.x * 64 + nl;
    if (node < NN) {
        const float4* g4 = (const float4*)g2;
        int start = cursor[node], n = cnt[node];
        float4 acc = g4[node * 4 + q];
        int e = start, end = start + n;
        for (; e + 3 < end; e += 4) {
            int r0 = csr_rid[e], r1 = csr_rid[e + 1], r2 = csr_rid[e + 2], r3 = csr_rid[e + 3];
            float4 v0 = g4[r0 * 4 + q], v1 = g4[r1 * 4 + q];
            float4 v2 = g4[r2 * 4 + q], v3 = g4[r3 * 4 + q];
            acc.x += (v0.x + v1.x) + (v2.x + v3.x);
            acc.y += (v0.y + v1.y) + (v2.y + v3.y);
            acc.z += (v0.z + v1.z) + (v2.z + v3.z);
            acc.w += (v0.w + v1.w) + (v2.w + v3.w);
        }
        for (; e < end; ++e) {
            float4 v = g4[csr_rid[e] * 4 + q];
            acc.x += v.x; acc.y += v.y; acc.z += v.z; acc.w += v.w;
        }
        float d = dis[node];
        vs[nl][q * 4 + 0] = d * acc.x;
        vs[nl][q * 4 + 1] = d * acc.y;
        vs[nl][q * 4 + 2] = d * acc.z;
        vs[nl][q * 4 + 3] = d * acc.w;
    }
    __syncthreads();
    int o = t & 63, grp = t >> 6;                // 4 waves x 16 nodes each
    for (int k = 0; k < 16; ++k) {
        int nl2 = grp * 16 + k;
        int node2 = blockIdx.x * 64 + nl2;
        if (node2 >= NN) break;
        float acc = b2[o];
#pragma unroll
        for (int c = 0; c < CH; ++c) acc += vs[nl2][c] * w2s[c][o];
        out[(size_t)node2 * CO + o] = 1.0f / (1.0f + __expf(-acc));
    }
}

extern "C" void kernel_launch(void* const* d_in, const int* in_sizes, int n_in,
                              void* d_out, int out_size, void* d_ws, size_t ws_size,
                              hipStream_t stream) {
    const float* x  = (const float*)d_in[0];
    const int*   ei = (const int*)d_in[1];
    const float* W1 = (const float*)d_in[2];
    const float* b1 = (const float*)d_in[3];
    const float* W2 = (const float*)d_in[4];
    const float* b2 = (const float*)d_in[5];
    float* out = (float*)d_out;

    const int* rows = ei;
    const int* cols = ei + NE;

    char* w = (char*)d_ws;
    int*   cnt     = (int*)w;                 w += 100096 * 4;
    int*   cursor  = (int*)w;                 w += 100096 * 4;
    float* dis     = (float*)w;               w += 100096 * 4;
    int*   bsum    = (int*)w;                 w += 128 * 4;
    int*   rank    = (int*)w;                 w += (size_t)NE * 4;
    int*   csr_rid = (int*)w;
    // rank buffer is dead after k_place; reuse it for g and g2 (exactly 2*NN*CH*4 = NE*4 bytes)
    float* g  = (float*)rank;
    float* g2 = g + (size_t)NN * CH;

    hipMemsetAsync(cnt, 0, NN * sizeof(int), stream);

    k_rank   <<<NE / 4 / 256,     256, 0, stream>>>(cols, cnt, rank);
    k_scan1  <<<98,              1024, 0, stream>>>(cnt, cursor, bsum, dis);
    k_scan2  <<<1,                128, 0, stream>>>(bsum);
    k_scan3  <<<(NN + 255) / 256, 256, 0, stream>>>(cursor, bsum);
    k_place  <<<NE / 4 / 256,     256, 0, stream>>>(rows, cols, rank, cursor, csr_rid);
    k_gemm1s <<<NN / 32,          256, 0, stream>>>(x, W1, dis, g);
    k_gather1<<<(NN + 63) / 64,   256, 0, stream>>>(csr_rid, cursor, cnt, dis, g, b1, g2);
    k_gather2<<<(NN + 63) / 64,   256, 0, stream>>>(csr_rid, cursor, cnt, dis, g2, W2, b2, out);
}

// Round 4
// 198.849 us; speedup vs baseline: 27.5531x; 1.6415x over previous
//
#include <hip/hip_runtime.h>

constexpr int NN  = 100000;
constexpr int NE  = 3200000;
constexpr int CIN = 128;
constexpr int CH  = 16;   // hidden
constexpr int CO  = 64;   // out

constexpr int NBKT  = 391;   // ceil(NN/256): bucket = dest >> 8
constexpr int CHUNK = 8192;  // edges per block in bucketing passes
constexpr int NBLK  = 391;   // ceil(NE/CHUNK)

// ---- atomic-free CSR build ----------------------------------------------

// per-block bucket histogram (LDS atomics only)
__global__ void __launch_bounds__(256) k_hist(const int* __restrict__ cols,
                                              int* __restrict__ blkhist) {
    __shared__ int h[NBKT];
    int t = threadIdx.x, blk = blockIdx.x;
    for (int i = t; i < NBKT; i += 256) h[i] = 0;
    __syncthreads();
    const int4* c4 = (const int4*)cols;
    int base = blk * (CHUNK / 4);
    for (int j = 0; j < CHUNK / 4 / 256; ++j) {
        int idx = base + j * 256 + t;
        if (idx < NE / 4) {
            int4 c = c4[idx];
            atomicAdd(&h[c.x >> 8], 1); atomicAdd(&h[c.y >> 8], 1);
            atomicAdd(&h[c.z >> 8], 1); atomicAdd(&h[c.w >> 8], 1);
        }
    }
    __syncthreads();
    for (int i = t; i < NBKT; i += 256) blkhist[i * NBLK + blk] = h[i];
}

// exclusive scan of each bucket row (over blocks); row sums -> btot
__global__ void __launch_bounds__(512) k_rowscan(int* __restrict__ blkhist,
                                                 int* __restrict__ btot) {
    __shared__ int sh[512];
    int t = threadIdx.x, b = blockIdx.x;
    int v = (t < NBLK) ? blkhist[b * NBLK + t] : 0;
    sh[t] = v;
    __syncthreads();
    for (int off = 1; off < 512; off <<= 1) {
        int a = (t >= off) ? sh[t - off] : 0;
        __syncthreads();
        sh[t] += a;
        __syncthreads();
    }
    if (t < NBLK) blkhist[b * NBLK + t] = sh[t] - v;
    if (t == 511) btot[b] = sh[511];
}

// exclusive scan of bucket totals -> bucket bases
__global__ void __launch_bounds__(512) k_bscan(const int* __restrict__ btot,
                                               int* __restrict__ bbase) {
    __shared__ int sh[512];
    int t = threadIdx.x;
    int v = (t < NBKT) ? btot[t] : 0;
    sh[t] = v;
    __syncthreads();
    for (int off = 1; off < 512; off <<= 1) {
        int a = (t >= off) ? sh[t - off] : 0;
        __syncthreads();
        sh[t] += a;
        __syncthreads();
    }
    if (t < NBKT) bbase[t] = sh[t] - v;
    if (t == NBKT - 1) bbase[NBKT] = sh[t];   // total == NE
}

// partition edges into buckets: ebuf[pos] = row | (c&255)<<17
__global__ void __launch_bounds__(256) k_sbucket(const int* __restrict__ rows,
                                                 const int* __restrict__ cols,
                                                 const int* __restrict__ blkhist,
                                                 const int* __restrict__ bbase,
                                                 int* __restrict__ ebuf) {
    __shared__ int cur[NBKT];
    int t = threadIdx.x, blk = blockIdx.x;
    for (int i = t; i < NBKT; i += 256) cur[i] = bbase[i] + blkhist[i * NBLK + blk];
    __syncthreads();
    const int4* r4 = (const int4*)rows;
    const int4* c4 = (const int4*)cols;
    int base = blk * (CHUNK / 4);
    for (int j = 0; j < CHUNK / 4 / 256; ++j) {
        int idx = base + j * 256 + t;
        if (idx < NE / 4) {
            int4 r = r4[idx];
            int4 c = c4[idx];
            int p;
            p = atomicAdd(&cur[c.x >> 8], 1); ebuf[p] = r.x | ((c.x & 255) << 17);
            p = atomicAdd(&cur[c.y >> 8], 1); ebuf[p] = r.y | ((c.y & 255) << 17);
            p = atomicAdd(&cur[c.z >> 8], 1); ebuf[p] = r.z | ((c.z & 255) << 17);
            p = atomicAdd(&cur[c.w >> 8], 1); ebuf[p] = r.w | ((c.w & 255) << 17);
        }
    }
}

// one block per bucket: fine CSR (cursor/cnt/dis + csr_rid), all counting in LDS
__global__ void __launch_bounds__(256) k_fine(const int* __restrict__ ebuf,
                                              const int* __restrict__ bbase,
                                              int* __restrict__ cursor,
                                              int* __restrict__ cnt,
                                              float* __restrict__ dis,
                                              int* __restrict__ csr_rid) {
    __shared__ int scnt[256], sloc[256], run[256];
    int t = threadIdx.x, b = blockIdx.x;
    scnt[t] = 0;
    __syncthreads();
    int base = bbase[b], n = bbase[b + 1] - base;
    for (int i = t; i < n; i += 256) {
        int pk = ebuf[base + i];
        atomicAdd(&scnt[pk >> 17], 1);
    }
    __syncthreads();
    int v = scnt[t];
    sloc[t] = v;
    __syncthreads();
    for (int off = 1; off < 256; off <<= 1) {
        int a = (t >= off) ? sloc[t - off] : 0;
        __syncthreads();
        sloc[t] += a;
        __syncthreads();
    }
    int excl = sloc[t] - v;
    int c = b * 256 + t;
    if (c < NN) {
        cursor[c] = base + excl;
        cnt[c]    = v;
        dis[c]    = rsqrtf((float)(v + 1));
    }
    run[t] = base + excl;
    __syncthreads();
    for (int i = t; i < n; i += 256) {
        int pk = ebuf[base + i];
        int pos = atomicAdd(&run[pk >> 17], 1);
        csr_rid[pos] = pk & 0x1FFFF;
    }
}

// ---- layer math ---------------------------------------------------------

// g = dis[node] * (x @ W1)
__global__ void __launch_bounds__(256) k_gemm1s(const float* __restrict__ x,
                                                const float* __restrict__ W1,
                                                const float* __restrict__ dis,
                                                float* __restrict__ g) {
    __shared__ float xs[32][CIN + 1];
    __shared__ float ws[CIN][CH];
    int t = threadIdx.x;
    int base = blockIdx.x * 32;                  // 100000 = 32*3125
    for (int i = t; i < CIN * CH; i += 256) ws[i >> 4][i & 15] = W1[i];
    const float4* xv = (const float4*)(x + (size_t)base * CIN);
    for (int i = t; i < 32 * CIN / 4; i += 256) {
        float4 v = xv[i];
        int r = i >> 5, cq = i & 31;
        xs[r][cq * 4 + 0] = v.x; xs[r][cq * 4 + 1] = v.y;
        xs[r][cq * 4 + 2] = v.z; xs[r][cq * 4 + 3] = v.w;
    }
    __syncthreads();
    int node = t >> 3;
    int c0 = (t & 7) * 2;
    float a0 = 0.f, a1 = 0.f;
#pragma unroll 8
    for (int k = 0; k < CIN; ++k) {
        float xk = xs[node][k];
        a0 += xk * ws[k][c0];
        a1 += xk * ws[k][c0 + 1];
    }
    float d = dis[base + node];
    float2* o = (float2*)(g + (size_t)(base + node) * CH + c0);
    *o = make_float2(a0 * d, a1 * d);
}

// layer-1 gather fused with mid: g2 = dis * relu(dis*(sum + self) + b1)
__global__ void __launch_bounds__(256) k_gather1(const int* __restrict__ csr_rid,
                                                 const int* __restrict__ cursor,
                                                 const int* __restrict__ cnt,
                                                 const float* __restrict__ dis,
                                                 const float* __restrict__ g,
                                                 const float* __restrict__ b1,
                                                 float* __restrict__ g2) {
    int t = threadIdx.x;
    int node = blockIdx.x * 64 + (t >> 2);
    if (node >= NN) return;
    int q = t & 3;
    const float4* g4 = (const float4*)g;
    int start = cursor[node], n = cnt[node];
    float4 acc = g4[node * 4 + q];               // self-loop term
    int e = start, end = start + n;
    for (; e + 3 < end; e += 4) {
        int r0 = csr_rid[e], r1 = csr_rid[e + 1], r2 = csr_rid[e + 2], r3 = csr_rid[e + 3];
        float4 v0 = g4[r0 * 4 + q], v1 = g4[r1 * 4 + q];
        float4 v2 = g4[r2 * 4 + q], v3 = g4[r3 * 4 + q];
        acc.x += (v0.x + v1.x) + (v2.x + v3.x);
        acc.y += (v0.y + v1.y) + (v2.y + v3.y);
        acc.z += (v0.z + v1.z) + (v2.z + v3.z);
        acc.w += (v0.w + v1.w) + (v2.w + v3.w);
    }
    for (; e < end; ++e) {
        float4 v = g4[csr_rid[e] * 4 + q];
        acc.x += v.x; acc.y += v.y; acc.z += v.z; acc.w += v.w;
    }
    float d = dis[node];
    float4 b = ((const float4*)b1)[q];
    float4 r;
    r.x = d * fmaxf(d * acc.x + b.x, 0.f);
    r.y = d * fmaxf(d * acc.y + b.y, 0.f);
    r.z = d * fmaxf(d * acc.z + b.z, 0.f);
    r.w = d * fmaxf(d * acc.w + b.w, 0.f);
    ((float4*)g2)[node * 4 + q] = r;
}

// layer-2 gather fused with final GEMM + sigmoid
__global__ void __launch_bounds__(256) k_gather2(const int* __restrict__ csr_rid,
                                                 const int* __restrict__ cursor,
                                                 const int* __restrict__ cnt,
                                                 const float* __restrict__ dis,
                                                 const float* __restrict__ g2,
                                                 const float* __restrict__ W2,
                                                 const float* __restrict__ b2,
                                                 float* __restrict__ out) {
    __shared__ float vs[64][CH + 1];
    __shared__ float w2s[CH][CO];
    int t = threadIdx.x;
    for (int i = t; i < CH * CO; i += 256) w2s[i >> 6][i & 63] = W2[i];
    int nl = t >> 2, q = t & 3;
    int node = blockIdx.x * 64 + nl;
    if (node < NN) {
        const float4* g4 = (const float4*)g2;
        int start = cursor[node], n = cnt[node];
        float4 acc = g4[node * 4 + q];
        int e = start, end = start + n;
        for (; e + 3 < end; e += 4) {
            int r0 = csr_rid[e], r1 = csr_rid[e + 1], r2 = csr_rid[e + 2], r3 = csr_rid[e + 3];
            float4 v0 = g4[r0 * 4 + q], v1 = g4[r1 * 4 + q];
            float4 v2 = g4[r2 * 4 + q], v3 = g4[r3 * 4 + q];
            acc.x += (v0.x + v1.x) + (v2.x + v3.x);
            acc.y += (v0.y + v1.y) + (v2.y + v3.y);
            acc.z += (v0.z + v1.z) + (v2.z + v3.z);
            acc.w += (v0.w + v1.w) + (v2.w + v3.w);
        }
        for (; e < end; ++e) {
            float4 v = g4[csr_rid[e] * 4 + q];
            acc.x += v.x; acc.y += v.y; acc.z += v.z; acc.w += v.w;
        }
        float d = dis[node];
        vs[nl][q * 4 + 0] = d * acc.x;
        vs[nl][q * 4 + 1] = d * acc.y;
        vs[nl][q * 4 + 2] = d * acc.z;
        vs[nl][q * 4 + 3] = d * acc.w;
    }
    __syncthreads();
    int o = t & 63, grp = t >> 6;                // 4 waves x 16 nodes each
    for (int k = 0; k < 16; ++k) {
        int nl2 = grp * 16 + k;
        int node2 = blockIdx.x * 64 + nl2;
        if (node2 >= NN) break;
        float acc = b2[o];
#pragma unroll
        for (int c = 0; c < CH; ++c) acc += vs[nl2][c] * w2s[c][o];
        out[(size_t)node2 * CO + o] = 1.0f / (1.0f + __expf(-acc));
    }
}

extern "C" void kernel_launch(void* const* d_in, const int* in_sizes, int n_in,
                              void* d_out, int out_size, void* d_ws, size_t ws_size,
                              hipStream_t stream) {
    const float* x  = (const float*)d_in[0];
    const int*   ei = (const int*)d_in[1];
    const float* W1 = (const float*)d_in[2];
    const float* b1 = (const float*)d_in[3];
    const float* W2 = (const float*)d_in[4];
    const float* b2 = (const float*)d_in[5];
    float* out = (float*)d_out;

    const int* rows = ei;
    const int* cols = ei + NE;

    char* w = (char*)d_ws;
    int*   cursor  = (int*)w;                 w += 100096 * 4;
    int*   cnt     = (int*)w;                 w += 100096 * 4;
    float* dis     = (float*)w;               w += 100096 * 4;
    int*   btot    = (int*)w;                 w += 512 * 4;
    int*   bbase   = (int*)w;                 w += 512 * 4;
    int*   ebuf    = (int*)w;                 w += (size_t)NE * 4;
    int*   csr_rid = (int*)w;
    // aliases: blkhist lives in csr_rid's space (dead before k_fine writes csr_rid);
    // g/g2 live in ebuf's space (ebuf dead after k_fine, before k_gemm1s writes g)
    int*   blkhist = csr_rid;                 // NBKT*NBLK = 152881 ints << NE
    float* g  = (float*)ebuf;
    float* g2 = g + (size_t)NN * CH;          // 2*NN*CH = NE exactly

    k_hist   <<<NBLK, 256, 0, stream>>>(cols, blkhist);
    k_rowscan<<<NBKT, 512, 0, stream>>>(blkhist, btot);
    k_bscan  <<<1,    512, 0, stream>>>(btot, bbase);
    k_sbucket<<<NBLK, 256, 0, stream>>>(rows, cols, blkhist, bbase, ebuf);
    k_fine   <<<NBKT, 256, 0, stream>>>(ebuf, bbase, cursor, cnt, dis, csr_rid);
    k_gemm1s <<<NN / 32,        256, 0, stream>>>(x, W1, dis, g);
    k_gather1<<<(NN + 63) / 64, 256, 0, stream>>>(csr_rid, cursor, cnt, dis, g, b1, g2);
    k_gather2<<<(NN + 63) / 64, 256, 0, stream>>>(csr_rid, cursor, cnt, dis, g2, W2, b2, out);
}

// Round 5
// 158.340 us; speedup vs baseline: 34.6022x; 1.2558x over previous
//
#include <hip/hip_runtime.h>
#include <hip/hip_fp16.h>

constexpr int NN  = 100000;
constexpr int NE  = 3200000;
constexpr int CIN = 128;
constexpr int CH  = 16;   // hidden
constexpr int CO  = 64;   // out

constexpr int NBKT  = 391;   // ceil(NN/256): bucket = dest >> 8
constexpr int CHUNK = 8192;  // edges per block in bucketing passes
constexpr int NBLK  = 391;   // ceil(NE/CHUNK)

// ---- atomic-free CSR build ----------------------------------------------

__global__ void __launch_bounds__(256) k_hist(const int* __restrict__ cols,
                                              int* __restrict__ blkhist) {
    __shared__ int h[NBKT];
    int t = threadIdx.x, blk = blockIdx.x;
    for (int i = t; i < NBKT; i += 256) h[i] = 0;
    __syncthreads();
    const int4* c4 = (const int4*)cols;
    int base = blk * (CHUNK / 4);
    for (int j = 0; j < CHUNK / 4 / 256; ++j) {
        int idx = base + j * 256 + t;
        if (idx < NE / 4) {
            int4 c = c4[idx];
            atomicAdd(&h[c.x >> 8], 1); atomicAdd(&h[c.y >> 8], 1);
            atomicAdd(&h[c.z >> 8], 1); atomicAdd(&h[c.w >> 8], 1);
        }
    }
    __syncthreads();
    for (int i = t; i < NBKT; i += 256) blkhist[i * NBLK + blk] = h[i];
}

__global__ void __launch_bounds__(512) k_rowscan(int* __restrict__ blkhist,
                                                 int* __restrict__ btot) {
    __shared__ int sh[512];
    int t = threadIdx.x, b = blockIdx.x;
    int v = (t < NBLK) ? blkhist[b * NBLK + t] : 0;
    sh[t] = v;
    __syncthreads();
    for (int off = 1; off < 512; off <<= 1) {
        int a = (t >= off) ? sh[t - off] : 0;
        __syncthreads();
        sh[t] += a;
        __syncthreads();
    }
    if (t < NBLK) blkhist[b * NBLK + t] = sh[t] - v;
    if (t == 511) btot[b] = sh[511];
}

__global__ void __launch_bounds__(512) k_bscan(const int* __restrict__ btot,
                                               int* __restrict__ bbase) {
    __shared__ int sh[512];
    int t = threadIdx.x;
    int v = (t < NBKT) ? btot[t] : 0;
    sh[t] = v;
    __syncthreads();
    for (int off = 1; off < 512; off <<= 1) {
        int a = (t >= off) ? sh[t - off] : 0;
        __syncthreads();
        sh[t] += a;
        __syncthreads();
    }
    if (t < NBKT) bbase[t] = sh[t] - v;
    if (t == NBKT - 1) bbase[NBKT] = sh[t];   // total == NE
}

__global__ void __launch_bounds__(256) k_sbucket(const int* __restrict__ rows,
                                                 const int* __restrict__ cols,
                                                 const int* __restrict__ blkhist,
                                                 const int* __restrict__ bbase,
                                                 int* __restrict__ ebuf) {
    __shared__ int cur[NBKT];
    int t = threadIdx.x, blk = blockIdx.x;
    for (int i = t; i < NBKT; i += 256) cur[i] = bbase[i] + blkhist[i * NBLK + blk];
    __syncthreads();
    const int4* r4 = (const int4*)rows;
    const int4* c4 = (const int4*)cols;
    int base = blk * (CHUNK / 4);
    for (int j = 0; j < CHUNK / 4 / 256; ++j) {
        int idx = base + j * 256 + t;
        if (idx < NE / 4) {
            int4 r = r4[idx];
            int4 c = c4[idx];
            int p;
            p = atomicAdd(&cur[c.x >> 8], 1); ebuf[p] = r.x | ((c.x & 255) << 17);
            p = atomicAdd(&cur[c.y >> 8], 1); ebuf[p] = r.y | ((c.y & 255) << 17);
            p = atomicAdd(&cur[c.z >> 8], 1); ebuf[p] = r.z | ((c.z & 255) << 17);
            p = atomicAdd(&cur[c.w >> 8], 1); ebuf[p] = r.w | ((c.w & 255) << 17);
        }
    }
}

__global__ void __launch_bounds__(256) k_fine(const int* __restrict__ ebuf,
                                              const int* __restrict__ bbase,
                                              int* __restrict__ cursor,
                                              int* __restrict__ cnt,
                                              float* __restrict__ dis,
                                              int* __restrict__ csr_rid) {
    __shared__ int scnt[256], sloc[256], run[256];
    int t = threadIdx.x, b = blockIdx.x;
    scnt[t] = 0;
    __syncthreads();
    int base = bbase[b], n = bbase[b + 1] - base;
    for (int i = t; i < n; i += 256) {
        int pk = ebuf[base + i];
        atomicAdd(&scnt[pk >> 17], 1);
    }
    __syncthreads();
    int v = scnt[t];
    sloc[t] = v;
    __syncthreads();
    for (int off = 1; off < 256; off <<= 1) {
        int a = (t >= off) ? sloc[t - off] : 0;
        __syncthreads();
        sloc[t] += a;
        __syncthreads();
    }
    int excl = sloc[t] - v;
    int c = b * 256 + t;
    if (c < NN) {
        cursor[c] = base + excl;
        cnt[c]    = v;
        dis[c]    = rsqrtf((float)(v + 1));
    }
    run[t] = base + excl;
    __syncthreads();
    for (int i = t; i < n; i += 256) {
        int pk = ebuf[base + i];
        int pos = atomicAdd(&run[pk >> 17], 1);
        csr_rid[pos] = pk & 0x1FFFF;
    }
}

// ---- layer math ---------------------------------------------------------

// gh (fp16) = dis[node] * (x @ W1)
__global__ void __launch_bounds__(256) k_gemm1s(const float* __restrict__ x,
                                                const float* __restrict__ W1,
                                                const float* __restrict__ dis,
                                                __half* __restrict__ gh) {
    __shared__ float xs[32][CIN + 1];
    __shared__ float ws[CIN][CH];
    int t = threadIdx.x;
    int base = blockIdx.x * 32;                  // 100000 = 32*3125
    for (int i = t; i < CIN * CH; i += 256) ws[i >> 4][i & 15] = W1[i];
    const float4* xv = (const float4*)(x + (size_t)base * CIN);
    for (int i = t; i < 32 * CIN / 4; i += 256) {
        float4 v = xv[i];
        int r = i >> 5, cq = i & 31;
        xs[r][cq * 4 + 0] = v.x; xs[r][cq * 4 + 1] = v.y;
        xs[r][cq * 4 + 2] = v.z; xs[r][cq * 4 + 3] = v.w;
    }
    __syncthreads();
    int node = t >> 3;
    int c0 = (t & 7) * 2;
    float a0 = 0.f, a1 = 0.f;
#pragma unroll 8
    for (int k = 0; k < CIN; ++k) {
        float xk = xs[node][k];
        a0 += xk * ws[k][c0];
        a1 += xk * ws[k][c0 + 1];
    }
    float d = dis[base + node];
    ((__half2*)gh)[((size_t)(base + node) * CH + c0) >> 1] = __floats2half2_rn(a0 * d, a1 * d);
}

__device__ __forceinline__ void acc_h4(float2 raw, float4& acc) {
    __half2 h01 = *(__half2*)&raw.x, h23 = *(__half2*)&raw.y;
    float2 f01 = __half22float2(h01), f23 = __half22float2(h23);
    acc.x += f01.x; acc.y += f01.y; acc.z += f23.x; acc.w += f23.y;
}

// layer-1 gather fused with mid: g2h = fp16( dis * relu(dis*(sum + self) + b1) )
__global__ void __launch_bounds__(256) k_gather1(const int* __restrict__ csr_rid,
                                                 const int* __restrict__ cursor,
                                                 const int* __restrict__ cnt,
                                                 const float* __restrict__ dis,
                                                 const __half* __restrict__ gh,
                                                 const float* __restrict__ b1,
                                                 __half* __restrict__ g2h) {
    int t = threadIdx.x;
    int node = blockIdx.x * 64 + (t >> 2);
    if (node >= NN) return;
    int q = t & 3;
    const float2* g4 = (const float2*)gh;        // 8 B = 4 halves per lane
    int start = cursor[node], n = cnt[node];
    float4 acc = make_float4(0.f, 0.f, 0.f, 0.f);
    acc_h4(g4[node * 4 + q], acc);               // self-loop term
    int e = start, end = start + n;
    for (; e + 7 < end; e += 8) {
        int r0 = csr_rid[e],     r1 = csr_rid[e + 1], r2 = csr_rid[e + 2], r3 = csr_rid[e + 3];
        int r4 = csr_rid[e + 4], r5 = csr_rid[e + 5], r6 = csr_rid[e + 6], r7 = csr_rid[e + 7];
        float2 v0 = g4[r0 * 4 + q], v1 = g4[r1 * 4 + q], v2 = g4[r2 * 4 + q], v3 = g4[r3 * 4 + q];
        float2 v4 = g4[r4 * 4 + q], v5 = g4[r5 * 4 + q], v6 = g4[r6 * 4 + q], v7 = g4[r7 * 4 + q];
        acc_h4(v0, acc); acc_h4(v1, acc); acc_h4(v2, acc); acc_h4(v3, acc);
        acc_h4(v4, acc); acc_h4(v5, acc); acc_h4(v6, acc); acc_h4(v7, acc);
    }
    for (; e < end; ++e) acc_h4(g4[csr_rid[e] * 4 + q], acc);
    float d = dis[node];
    float4 b = ((const float4*)b1)[q];
    __half2 p0 = __floats2half2_rn(d * fmaxf(d * acc.x + b.x, 0.f),
                                   d * fmaxf(d * acc.y + b.y, 0.f));
    __half2 p1 = __floats2half2_rn(d * fmaxf(d * acc.z + b.z, 0.f),
                                   d * fmaxf(d * acc.w + b.w, 0.f));
    uint2 wv;
    wv.x = *(unsigned int*)&p0;
    wv.y = *(unsigned int*)&p1;
    ((uint2*)g2h)[node * 4 + q] = wv;
}

// layer-2 gather fused with final GEMM + sigmoid
__global__ void __launch_bounds__(256) k_gather2(const int* __restrict__ csr_rid,
                                                 const int* __restrict__ cursor,
                                                 const int* __restrict__ cnt,
                                                 const float* __restrict__ dis,
                                                 const __half* __restrict__ g2h,
                                                 const float* __restrict__ W2,
                                                 const float* __restrict__ b2,
                                                 float* __restrict__ out) {
    __shared__ float vs[64][CH + 1];
    __shared__ float w2s[CH][CO];
    int t = threadIdx.x;
    for (int i = t; i < CH * CO; i += 256) w2s[i >> 6][i & 63] = W2[i];
    int nl = t >> 2, q = t & 3;
    int node = blockIdx.x * 64 + nl;
    if (node < NN) {
        const float2* g4 = (const float2*)g2h;
        int start = cursor[node], n = cnt[node];
        float4 acc = make_float4(0.f, 0.f, 0.f, 0.f);
        acc_h4(g4[node * 4 + q], acc);
        int e = start, end = start + n;
        for (; e + 7 < end; e += 8) {
            int r0 = csr_rid[e],     r1 = csr_rid[e + 1], r2 = csr_rid[e + 2], r3 = csr_rid[e + 3];
            int r4 = csr_rid[e + 4], r5 = csr_rid[e + 5], r6 = csr_rid[e + 6], r7 = csr_rid[e + 7];
            float2 v0 = g4[r0 * 4 + q], v1 = g4[r1 * 4 + q], v2 = g4[r2 * 4 + q], v3 = g4[r3 * 4 + q];
            float2 v4 = g4[r4 * 4 + q], v5 = g4[r5 * 4 + q], v6 = g4[r6 * 4 + q], v7 = g4[r7 * 4 + q];
            acc_h4(v0, acc); acc_h4(v1, acc); acc_h4(v2, acc); acc_h4(v3, acc);
            acc_h4(v4, acc); acc_h4(v5, acc); acc_h4(v6, acc); acc_h4(v7, acc);
        }
        for (; e < end; ++e) acc_h4(g4[csr_rid[e] * 4 + q], acc);
        float d = dis[node];
        vs[nl][q * 4 + 0] = d * acc.x;
        vs[nl][q * 4 + 1] = d * acc.y;
        vs[nl][q * 4 + 2] = d * acc.z;
        vs[nl][q * 4 + 3] = d * acc.w;
    }
    __syncthreads();
    int o = t & 63, grp = t >> 6;                // 4 waves x 16 nodes each
    for (int k = 0; k < 16; ++k) {
        int nl2 = grp * 16 + k;
        int node2 = blockIdx.x * 64 + nl2;
        if (node2 >= NN) break;
        float acc = b2[o];
#pragma unroll
        for (int c = 0; c < CH; ++c) acc += vs[nl2][c] * w2s[c][o];
        out[(size_t)node2 * CO + o] = 1.0f / (1.0f + __expf(-acc));
    }
}

extern "C" void kernel_launch(void* const* d_in, const int* in_sizes, int n_in,
                              void* d_out, int out_size, void* d_ws, size_t ws_size,
                              hipStream_t stream) {
    const float* x  = (const float*)d_in[0];
    const int*   ei = (const int*)d_in[1];
    const float* W1 = (const float*)d_in[2];
    const float* b1 = (const float*)d_in[3];
    const float* W2 = (const float*)d_in[4];
    const float* b2 = (const float*)d_in[5];
    float* out = (float*)d_out;

    const int* rows = ei;
    const int* cols = ei + NE;

    char* w = (char*)d_ws;
    int*   cursor  = (int*)w;                 w += 100096 * 4;
    int*   cnt     = (int*)w;                 w += 100096 * 4;
    float* dis     = (float*)w;               w += 100096 * 4;
    int*   btot    = (int*)w;                 w += 512 * 4;
    int*   bbase   = (int*)w;                 w += 512 * 4;
    int*   ebuf    = (int*)w;                 w += (size_t)NE * 4;
    int*   csr_rid = (int*)w;
    // aliases: blkhist in csr_rid's space (dead before k_fine writes csr_rid);
    // fp16 feature tables in ebuf's space (ebuf dead after k_fine)
    int*    blkhist = csr_rid;                // NBKT*NBLK ints << NE
    __half* gh  = (__half*)ebuf;              // NN*CH halves = 3.2 MB
    __half* g2h = gh + (size_t)NN * CH;       // 3.2 MB

    k_hist   <<<NBLK, 256, 0, stream>>>(cols, blkhist);
    k_rowscan<<<NBKT, 512, 0, stream>>>(blkhist, btot);
    k_bscan  <<<1,    512, 0, stream>>>(btot, bbase);
    k_sbucket<<<NBLK, 256, 0, stream>>>(rows, cols, blkhist, bbase, ebuf);
    k_fine   <<<NBKT, 256, 0, stream>>>(ebuf, bbase, cursor, cnt, dis, csr_rid);
    k_gemm1s <<<NN / 32,        256, 0, stream>>>(x, W1, dis, gh);
    k_gather1<<<(NN + 63) / 64, 256, 0, stream>>>(csr_rid, cursor, cnt, dis, gh, b1, g2h);
    k_gather2<<<(NN + 63) / 64, 256, 0, stream>>>(csr_rid, cursor, cnt, dis, g2h, W2, b2, out);
}

// Round 6
// 149.264 us; speedup vs baseline: 36.7060x; 1.0608x over previous
//
#include <hip/hip_runtime.h>
#include <hip/hip_fp16.h>

constexpr int NN  = 100000;
constexpr int NE  = 3200000;
constexpr int CIN = 128;
constexpr int CH  = 16;   // hidden
constexpr int CO  = 64;   // out

constexpr int NBKT  = 391;   // ceil(NN/256): bucket = dest >> 8
constexpr int CHUNK = 8192;  // edges per block in bucketing passes
constexpr int NBLK  = 391;   // ceil(NE/CHUNK)

// ---- atomic-free CSR build ----------------------------------------------

__global__ void __launch_bounds__(256) k_hist(const int* __restrict__ cols,
                                              int* __restrict__ blkhist) {
    __shared__ int h[NBKT];
    int t = threadIdx.x, blk = blockIdx.x;
    for (int i = t; i < NBKT; i += 256) h[i] = 0;
    __syncthreads();
    const int4* c4 = (const int4*)cols;
    int base = blk * (CHUNK / 4);
    for (int j = 0; j < CHUNK / 4 / 256; ++j) {
        int idx = base + j * 256 + t;
        if (idx < NE / 4) {
            int4 c = c4[idx];
            atomicAdd(&h[c.x >> 8], 1); atomicAdd(&h[c.y >> 8], 1);
            atomicAdd(&h[c.z >> 8], 1); atomicAdd(&h[c.w >> 8], 1);
        }
    }
    __syncthreads();
    for (int i = t; i < NBKT; i += 256) blkhist[i * NBLK + blk] = h[i];
}

__global__ void __launch_bounds__(512) k_rowscan(int* __restrict__ blkhist,
                                                 int* __restrict__ btot) {
    __shared__ int sh[512];
    int t = threadIdx.x, b = blockIdx.x;
    int v = (t < NBLK) ? blkhist[b * NBLK + t] : 0;
    sh[t] = v;
    __syncthreads();
    for (int off = 1; off < 512; off <<= 1) {
        int a = (t >= off) ? sh[t - off] : 0;
        __syncthreads();
        sh[t] += a;
        __syncthreads();
    }
    if (t < NBLK) blkhist[b * NBLK + t] = sh[t] - v;
    if (t == 511) btot[b] = sh[511];
}

// generic 391-entry exclusive scan (used for btot->bbase and pbtot->pbase)
__global__ void __launch_bounds__(512) k_bscan(const int* __restrict__ in,
                                               int* __restrict__ out) {
    __shared__ int sh[512];
    int t = threadIdx.x;
    int v = (t < NBKT) ? in[t] : 0;
    sh[t] = v;
    __syncthreads();
    for (int off = 1; off < 512; off <<= 1) {
        int a = (t >= off) ? sh[t - off] : 0;
        __syncthreads();
        sh[t] += a;
        __syncthreads();
    }
    if (t < NBKT) out[t] = sh[t] - v;
    if (t == NBKT - 1) out[NBKT] = sh[t];
}

__global__ void __launch_bounds__(256) k_sbucket(const int* __restrict__ rows,
                                                 const int* __restrict__ cols,
                                                 const int* __restrict__ blkhist,
                                                 const int* __restrict__ bbase,
                                                 int* __restrict__ ebuf) {
    __shared__ int cur[NBKT];
    int t = threadIdx.x, blk = blockIdx.x;
    for (int i = t; i < NBKT; i += 256) cur[i] = bbase[i] + blkhist[i * NBLK + blk];
    __syncthreads();
    const int4* r4 = (const int4*)rows;
    const int4* c4 = (const int4*)cols;
    int base = blk * (CHUNK / 4);
    for (int j = 0; j < CHUNK / 4 / 256; ++j) {
        int idx = base + j * 256 + t;
        if (idx < NE / 4) {
            int4 r = r4[idx];
            int4 c = c4[idx];
            int p;
            p = atomicAdd(&cur[c.x >> 8], 1); ebuf[p] = r.x | ((c.x & 255) << 17);
            p = atomicAdd(&cur[c.y >> 8], 1); ebuf[p] = r.y | ((c.y & 255) << 17);
            p = atomicAdd(&cur[c.z >> 8], 1); ebuf[p] = r.z | ((c.z & 255) << 17);
            p = atomicAdd(&cur[c.w >> 8], 1); ebuf[p] = r.w | ((c.w & 255) << 17);
        }
    }
}

// phase A: per-node counts, padded (x4) local scan, bucket padded totals
__global__ void __launch_bounds__(256) k_fineA(const int* __restrict__ ebuf,
                                               const int* __restrict__ bbase,
                                               int* __restrict__ cursor,
                                               int* __restrict__ cnt,
                                               float* __restrict__ dis,
                                               int* __restrict__ pbtot) {
    __shared__ int scnt[256], sloc[256];
    int t = threadIdx.x, b = blockIdx.x;
    scnt[t] = 0;
    __syncthreads();
    int base = bbase[b], n = bbase[b + 1] - base;
    for (int i = t; i < n; i += 256) atomicAdd(&scnt[ebuf[base + i] >> 17], 1);
    __syncthreads();
    int v = scnt[t];
    int v4 = (v + 3) & ~3;
    sloc[t] = v4;
    __syncthreads();
    for (int off = 1; off < 256; off <<= 1) {
        int a = (t >= off) ? sloc[t - off] : 0;
        __syncthreads();
        sloc[t] += a;
        __syncthreads();
    }
    int excl4 = sloc[t] - v4;
    int c = b * 256 + t;
    if (c < NN) {
        cursor[c] = excl4;                    // temp: bucket-relative padded offset
        cnt[c]    = v;
        dis[c]    = rsqrtf((float)(v + 1));
    }
    if (t == 255) pbtot[b] = sloc[255];
}

// phase B: place rids at padded offsets; pad-fill with dummy rid = NN
__global__ void __launch_bounds__(256) k_fineB(const int* __restrict__ ebuf,
                                               const int* __restrict__ bbase,
                                               const int* __restrict__ pbase,
                                               int* __restrict__ cursor,
                                               const int* __restrict__ cnt,
                                               int* __restrict__ csr_rid) {
    __shared__ int run[256];
    int t = threadIdx.x, b = blockIdx.x;
    int pb = pbase[b];
    int c = b * 256 + t;
    int cur = 0, myn = 0;
    if (c < NN) {
        cur = pb + cursor[c];
        myn = cnt[c];
        cursor[c] = cur;                      // final global cursor
    }
    run[t] = cur;
    __syncthreads();
    int base = bbase[b], n = bbase[b + 1] - base;
    for (int i = t; i < n; i += 256) {
        int pk = ebuf[base + i];
        int pos = atomicAdd(&run[pk >> 17], 1);
        csr_rid[pos] = pk & 0x1FFFF;
    }
    __syncthreads();
    if (c < NN) {
        int p = cur + myn, p4 = cur + ((myn + 3) & ~3);
        for (; p < p4; ++p) csr_rid[p] = NN;  // dummy -> zero feature row
    }
}

// ---- layer math ---------------------------------------------------------

// gh (fp16) = dis[node] * (x @ W1)
__global__ void __launch_bounds__(256) k_gemm1s(const float* __restrict__ x,
                                                const float* __restrict__ W1,
                                                const float* __restrict__ dis,
                                                __half* __restrict__ gh) {
    __shared__ float xs[32][CIN + 1];
    __shared__ float ws[CIN][CH];
    int t = threadIdx.x;
    int base = blockIdx.x * 32;                  // 100000 = 32*3125
    for (int i = t; i < CIN * CH; i += 256) ws[i >> 4][i & 15] = W1[i];
    const float4* xv = (const float4*)(x + (size_t)base * CIN);
    for (int i = t; i < 32 * CIN / 4; i += 256) {
        float4 v = xv[i];
        int r = i >> 5, cq = i & 31;
        xs[r][cq * 4 + 0] = v.x; xs[r][cq * 4 + 1] = v.y;
        xs[r][cq * 4 + 2] = v.z; xs[r][cq * 4 + 3] = v.w;
    }
    __syncthreads();
    int node = t >> 3;
    int c0 = (t & 7) * 2;
    float a0 = 0.f, a1 = 0.f;
#pragma unroll 8
    for (int k = 0; k < CIN; ++k) {
        float xk = xs[node][k];
        a0 += xk * ws[k][c0];
        a1 += xk * ws[k][c0 + 1];
    }
    float d = dis[base + node];
    ((__half2*)gh)[((size_t)(base + node) * CH + c0) >> 1] = __floats2half2_rn(a0 * d, a1 * d);
}

// zero the dummy feature rows (row NN of both tables)
__global__ void k_zrow(__half* __restrict__ gh, __half* __restrict__ g2h) {
    int t = threadIdx.x;
    if (t < CH) {
        gh [(size_t)NN * CH + t] = __float2half(0.f);
        g2h[(size_t)NN * CH + t] = __float2half(0.f);
    }
}

__device__ __forceinline__ void acc_h4(float2 raw, float4& acc) {
    __half2 h01 = *(__half2*)&raw.x, h23 = *(__half2*)&raw.y;
    float2 f01 = __half22float2(h01), f23 = __half22float2(h23);
    acc.x += f01.x; acc.y += f01.y; acc.z += f23.x; acc.w += f23.y;
}

// 8 lanes/node: q = channel quad (t&3), h = edge half ((t>>2)&1)
// layer-1: g2h = fp16( dis * relu(dis*(sum + self) + b1) )
__global__ void __launch_bounds__(256) k_gather1(const int* __restrict__ csr_rid,
                                                 const int* __restrict__ cursor,
                                                 const int* __restrict__ cnt,
                                                 const float* __restrict__ dis,
                                                 const __half* __restrict__ gh,
                                                 const float* __restrict__ b1,
                                                 __half* __restrict__ g2h) {
    int t = threadIdx.x;
    int node = blockIdx.x * 32 + (t >> 3);
    if (node >= NN) return;
    int q = t & 3, h = (t >> 2) & 1;
    const float2* g4 = (const float2*)gh;
    int start = cursor[node];                    // 4-aligned
    int nb = (cnt[node] + 3) >> 2;               // int4 blocks
    const int4* I = (const int4*)(csr_rid + start);
    float4 acc = make_float4(0.f, 0.f, 0.f, 0.f);
    int b = h;
    for (; b + 2 < nb; b += 4) {
        int4 i0 = I[b], i1 = I[b + 2];
        float2 v0 = g4[i0.x * 4 + q], v1 = g4[i0.y * 4 + q];
        float2 v2 = g4[i0.z * 4 + q], v3 = g4[i0.w * 4 + q];
        float2 w0 = g4[i1.x * 4 + q], w1 = g4[i1.y * 4 + q];
        float2 w2 = g4[i1.z * 4 + q], w3 = g4[i1.w * 4 + q];
        acc_h4(v0, acc); acc_h4(v1, acc); acc_h4(v2, acc); acc_h4(v3, acc);
        acc_h4(w0, acc); acc_h4(w1, acc); acc_h4(w2, acc); acc_h4(w3, acc);
    }
    for (; b < nb; b += 2) {
        int4 i0 = I[b];
        float2 v0 = g4[i0.x * 4 + q], v1 = g4[i0.y * 4 + q];
        float2 v2 = g4[i0.z * 4 + q], v3 = g4[i0.w * 4 + q];
        acc_h4(v0, acc); acc_h4(v1, acc); acc_h4(v2, acc); acc_h4(v3, acc);
    }
    acc.x += __shfl_xor(acc.x, 4);
    acc.y += __shfl_xor(acc.y, 4);
    acc.z += __shfl_xor(acc.z, 4);
    acc.w += __shfl_xor(acc.w, 4);
    if (h == 0) {
        acc_h4(g4[node * 4 + q], acc);           // self-loop
        float d = dis[node];
        float4 bb = ((const float4*)b1)[q];
        __half2 p0 = __floats2half2_rn(d * fmaxf(d * acc.x + bb.x, 0.f),
                                       d * fmaxf(d * acc.y + bb.y, 0.f));
        __half2 p1 = __floats2half2_rn(d * fmaxf(d * acc.z + bb.z, 0.f),
                                       d * fmaxf(d * acc.w + bb.w, 0.f));
        uint2 wv;
        wv.x = *(unsigned int*)&p0;
        wv.y = *(unsigned int*)&p1;
        ((uint2*)g2h)[node * 4 + q] = wv;
    }
}

// layer-2 gather fused with final GEMM + sigmoid (32 nodes/block)
__global__ void __launch_bounds__(256) k_gather2(const int* __restrict__ csr_rid,
                                                 const int* __restrict__ cursor,
                                                 const int* __restrict__ cnt,
                                                 const float* __restrict__ dis,
                                                 const __half* __restrict__ g2h,
                                                 const float* __restrict__ W2,
                                                 const float* __restrict__ b2,
                                                 float* __restrict__ out) {
    __shared__ float vs[32][CH + 1];
    __shared__ float w2s[CH][CO];
    int t = threadIdx.x;
    for (int i = t; i < CH * CO; i += 256) w2s[i >> 6][i & 63] = W2[i];
    int nl = t >> 3, q = t & 3, h = (t >> 2) & 1;
    int node = blockIdx.x * 32 + nl;
    if (node < NN) {
        const float2* g4 = (const float2*)g2h;
        int start = cursor[node];
        int nb = (cnt[node] + 3) >> 2;
        const int4* I = (const int4*)(csr_rid + start);
        float4 acc = make_float4(0.f, 0.f, 0.f, 0.f);
        int b = h;
        for (; b + 2 < nb; b += 4) {
            int4 i0 = I[b], i1 = I[b + 2];
            float2 v0 = g4[i0.x * 4 + q], v1 = g4[i0.y * 4 + q];
            float2 v2 = g4[i0.z * 4 + q], v3 = g4[i0.w * 4 + q];
            float2 w0 = g4[i1.x * 4 + q], w1 = g4[i1.y * 4 + q];
            float2 w2 = g4[i1.z * 4 + q], w3 = g4[i1.w * 4 + q];
            acc_h4(v0, acc); acc_h4(v1, acc); acc_h4(v2, acc); acc_h4(v3, acc);
            acc_h4(w0, acc); acc_h4(w1, acc); acc_h4(w2, acc); acc_h4(w3, acc);
        }
        for (; b < nb; b += 2) {
            int4 i0 = I[b];
            float2 v0 = g4[i0.x * 4 + q], v1 = g4[i0.y * 4 + q];
            float2 v2 = g4[i0.z * 4 + q], v3 = g4[i0.w * 4 + q];
            acc_h4(v0, acc); acc_h4(v1, acc); acc_h4(v2, acc); acc_h4(v3, acc);
        }
        acc.x += __shfl_xor(acc.x, 4);
        acc.y += __shfl_xor(acc.y, 4);
        acc.z += __shfl_xor(acc.z, 4);
        acc.w += __shfl_xor(acc.w, 4);
        if (h == 0) {
            acc_h4(g4[node * 4 + q], acc);       // self-loop
            float d = dis[node];
            vs[nl][q * 4 + 0] = d * acc.x;
            vs[nl][q * 4 + 1] = d * acc.y;
            vs[nl][q * 4 + 2] = d * acc.z;
            vs[nl][q * 4 + 3] = d * acc.w;
        }
    }
    __syncthreads();
    int o = t & 63, grp = t >> 6;                // 4 groups x 8 nodes each
    for (int k = 0; k < 8; ++k) {
        int nl2 = grp * 8 + k;
        int node2 = blockIdx.x * 32 + nl2;
        if (node2 >= NN) break;
        float acc = b2[o];
#pragma unroll
        for (int c = 0; c < CH; ++c) acc += vs[nl2][c] * w2s[c][o];
        out[(size_t)node2 * CO + o] = 1.0f / (1.0f + __expf(-acc));
    }
}

extern "C" void kernel_launch(void* const* d_in, const int* in_sizes, int n_in,
                              void* d_out, int out_size, void* d_ws, size_t ws_size,
                              hipStream_t stream) {
    const float* x  = (const float*)d_in[0];
    const int*   ei = (const int*)d_in[1];
    const float* W1 = (const float*)d_in[2];
    const float* b1 = (const float*)d_in[3];
    const float* W2 = (const float*)d_in[4];
    const float* b2 = (const float*)d_in[5];
    float* out = (float*)d_out;

    const int* rows = ei;
    const int* cols = ei + NE;

    char* w = (char*)d_ws;
    int*   cursor  = (int*)w;                 w += 100096 * 4;
    int*   cnt     = (int*)w;                 w += 100096 * 4;
    float* dis     = (float*)w;               w += 100096 * 4;
    int*   btot    = (int*)w;                 w += 512 * 4;
    int*   bbase   = (int*)w;                 w += 512 * 4;
    int*   pbtot   = (int*)w;                 w += 512 * 4;
    int*   pbase   = (int*)w;                 w += 512 * 4;
    int*   ebuf    = (int*)w;                 w += (size_t)NE * 4;
    int*   csr_rid = (int*)w;                 // NE + 3*NN (padded) ints
    // aliases: blkhist in csr_rid's space (dead before k_fineB writes csr_rid);
    // fp16 tables in ebuf's space (ebuf dead after k_fineB). Each table has
    // NN+1 rows (row NN = zeros for padding dummies).
    int*    blkhist = csr_rid;
    __half* gh  = (__half*)ebuf;              // (NN+1)*CH halves
    __half* g2h = gh + (size_t)(NN + 1) * CH;

    k_hist   <<<NBLK, 256, 0, stream>>>(cols, blkhist);
    k_rowscan<<<NBKT, 512, 0, stream>>>(blkhist, btot);
    k_bscan  <<<1,    512, 0, stream>>>(btot, bbase);
    k_sbucket<<<NBLK, 256, 0, stream>>>(rows, cols, blkhist, bbase, ebuf);
    k_fineA  <<<NBKT, 256, 0, stream>>>(ebuf, bbase, cursor, cnt, dis, pbtot);
    k_bscan  <<<1,    512, 0, stream>>>(pbtot, pbase);
    k_fineB  <<<NBKT, 256, 0, stream>>>(ebuf, bbase, pbase, cursor, cnt, csr_rid);
    k_gemm1s <<<NN / 32,        256, 0, stream>>>(x, W1, dis, gh);
    k_zrow   <<<1, 64, 0, stream>>>(gh, g2h);
    k_gather1<<<(NN + 31) / 32, 256, 0, stream>>>(csr_rid, cursor, cnt, dis, gh, b1, g2h);
    k_gather2<<<(NN + 31) / 32, 256, 0, stream>>>(csr_rid, cursor, cnt, dis, g2h, W2, b2, out);
}